// Round 9
// baseline (125.470 us; speedup 1.0000x reference)
//
#include <hip/hip_runtime.h>
#include <math.h>

// ---------------------------------------------------------------------------
// NormalDistributionChecker1D, round 9 — async global->LDS staging for MLP.
// r1-r8 evidence: both streaming passes cap at ~1.6-2 TB/s effective. The
// compiler re-serializes every source-level load batch (r2 VGPR=32, r4
// VGPR=24), leaving ~1 dwordx4 in flight per wave (~2.7 GB/s/wave). Fix:
// __builtin_amdgcn_global_load_lds (no VGPR dest -> cannot be serialized),
// 8 x 1KB outstanding per wave into wave-private LDS, double-buffered 8KB
// halves, next batch issued before consuming the current. 256 blocks
// (1/CU) also minimizes the suspected ~35ns/block dispatch cost.
// Exact-fit fast path (n4 == 256*256*64, true at n=16.7M); generic r8
// fallback otherwise. Math identical to r8 (absmax 0.0).
// ---------------------------------------------------------------------------

#if __has_builtin(__builtin_amdgcn_exp2f)
#define EXP2F(x) __builtin_amdgcn_exp2f(x)
#else
#define EXP2F(x) exp2f(x)
#endif
#if __has_builtin(__builtin_amdgcn_rcpf)
#define RCPF(x) __builtin_amdgcn_rcpf(x)
#else
#define RCPF(x) (1.0f / (x))
#endif

#define NBLK 256
// s_waitcnt imm (gfx9 encoding): vmcnt=0, expcnt=7 (ignore), lgkmcnt=15 (ignore)
#define WAITCNT_VM0 0x0f70

typedef const __attribute__((address_space(1))) unsigned int* gas1_u32p;
typedef __attribute__((address_space(3))) unsigned int* las3_u32p;

static __device__ __forceinline__ void async_load16(const float4* g, float4* l) {
    __builtin_amdgcn_global_load_lds((gas1_u32p)(const void*)g,
                                     (las3_u32p)(void*)l, 16, 0, 0);
}

static __device__ __forceinline__ double wave_reduce_d(double v) {
#pragma unroll
    for (int off = 32; off > 0; off >>= 1) v += __shfl_down(v, off);
    return v;
}

__device__ __constant__ double d_ZS[9] = {
    -1.2815516, -0.8416212, -0.5244005, -0.2533471, 0.0,
    0.2533471,  0.5244005,  0.8416212,  1.2815516};

__device__ void epilogue(const double* cum, float* out, int n) {
    const double CRIT[9] = {14.683657, 12.242145, 10.656372, 9.413640, 8.342832,
                            7.357034,  6.393306,  5.380053,  4.168159};
    const double nd = (double)n;
    double actual[10];
    actual[0] = cum[0];
#pragma unroll
    for (int k = 1; k < 9; ++k) actual[k] = cum[k] - cum[k - 1];
    actual[9] = nd - cum[8];
    const double expected = nd * (double)0.1f;
    const double denom = expected + 1e-7;
    double chi2 = 0.0;
#pragma unroll
    for (int j = 0; j < 10; ++j) {
        double d = actual[j] - expected;
        chi2 += d * d / denom;
    }
    double dneg[9], m = -1e300;
#pragma unroll
    for (int k = 0; k < 9; ++k) {
        dneg[k] = -fabs(chi2 - CRIT[k]);
        if (dneg[k] > m) m = dneg[k];
    }
    double W = 0.0, PQ = 0.0;
#pragma unroll
    for (int k = 0; k < 9; ++k) {
        double w = exp(dneg[k] - m);
        W += w;
        PQ += w * (0.1 * (double)(k + 1));
    }
    double p = 1.0 - PQ / W;
    double excess = (chi2 - 14.683657) / 100.0;
    if (excess < 0.0) excess = 0.0;
    out[0] = (float)(p + excess);
}

// Exact-fit layout (n4 == NBLK*256*64 = 4,194,304 float4):
//   block b owns float4s [b*16384, +16384); wave w sub-owns [w*4096, +4096);
//   batch u (0..7) = 512 float4 = 8 rounds x (64 lanes x 16B).
// stage[wid][buf][512]: wave-private 8KB halves, double-buffered.

// ws layout (double): [0..2*NBLK) part1 | [2*NBLK..2*NBLK+9*NBLK) part2
__global__ __launch_bounds__(256) void pass1_stats(const float* __restrict__ x,
                                                   double* __restrict__ part1, int n) {
    const int tx = threadIdx.x;
    const int lane = tx & 63, wid = tx >> 6;
    const int n4 = n >> 2;
    const float4* __restrict__ x4 = (const float4*)x;
    __shared__ float4 stage[4][2][512];  // 64 KB

    float fs = 0.f, fss = 0.f;

    if (n4 == NBLK * 256 * 64 && (n & 3) == 0) {
        const float4* wbase = x4 + blockIdx.x * 16384 + wid * 4096;
        float4* sbuf0 = &stage[wid][0][0];
        float4* sbuf1 = &stage[wid][1][0];
        // issue batch 0
#pragma unroll
        for (int r = 0; r < 8; ++r) async_load16(wbase + r * 64 + lane, sbuf0 + r * 64);
        for (int u = 0; u < 8; ++u) {
            float4* cur = (u & 1) ? sbuf1 : sbuf0;
            float4* nxt = (u & 1) ? sbuf0 : sbuf1;
            __builtin_amdgcn_s_waitcnt(WAITCNT_VM0);  // batch u landed
            if (u < 7) {
                const float4* gb = wbase + (u + 1) * 512;
#pragma unroll
                for (int r = 0; r < 8; ++r) async_load16(gb + r * 64 + lane, nxt + r * 64);
            }
#pragma unroll
            for (int r = 0; r < 8; ++r) {
                float4 v = cur[r * 64 + lane];
                fs += (v.x + v.y) + (v.z + v.w);
                fss = fmaf(v.x, v.x, fss); fss = fmaf(v.y, v.y, fss);
                fss = fmaf(v.z, v.z, fss); fss = fmaf(v.w, v.w, fss);
            }
        }
    } else {  // generic fallback (r8 path)
        const int tid = blockIdx.x * 256 + tx;
        const int nthreads = NBLK * 256;
        for (int i = tid; i < n4; i += nthreads) {
            float4 v = x4[i];
            fs += (v.x + v.y) + (v.z + v.w);
            fss = fmaf(v.x, v.x, fss); fss = fmaf(v.y, v.y, fss);
            fss = fmaf(v.z, v.z, fss); fss = fmaf(v.w, v.w, fss);
        }
        if (blockIdx.x == 0 && tx == 0) {
            for (int j = n4 << 2; j < n; ++j) {
                float v = x[j];
                fs += v;
                fss = fmaf(v, v, fss);
            }
        }
    }

    double s = wave_reduce_d((double)fs);
    double ss = wave_reduce_d((double)fss);
    __shared__ double sm[4][2];
    if (lane == 0) { sm[wid][0] = s; sm[wid][1] = ss; }
    __syncthreads();
    if (tx == 0) {
        part1[2 * blockIdx.x] = (sm[0][0] + sm[1][0]) + (sm[2][0] + sm[3][0]);
        part1[2 * blockIdx.x + 1] = (sm[0][1] + sm[1][1]) + (sm[2][1] + sm[3][1]);
    }
}

__global__ __launch_bounds__(256) void pass2_cum(const float* __restrict__ x,
                                                 const double* __restrict__ part1,
                                                 double* __restrict__ part2, int n) {
    const int tx = threadIdx.x;
    const int lane = tx & 63, wid = tx >> 6;
    __shared__ float4 stage[4][2][512];  // 64 KB
    __shared__ double sm[4][9];
    __shared__ float sConst[11];  // [0]=S/2 [1]=B/2 [2..10]=2^(-C_k/2)

    {   // inline fixed-order stats reduce (identical in every block)
        double s = 0.0, ss = 0.0;
        for (int b = tx; b < NBLK; b += 256) {
            s += part1[2 * b];
            ss += part1[2 * b + 1];
        }
        double rs = wave_reduce_d(s);
        double rss = wave_reduce_d(ss);
        if (lane == 0) { sm[wid][0] = rs; sm[wid][1] = rss; }
        __syncthreads();
        if (tx == 0) {
            double ts = (sm[0][0] + sm[1][0]) + (sm[2][0] + sm[3][0]);
            double tss = (sm[0][1] + sm[1][1]) + (sm[2][1] + sm[3][1]);
            const double Ld = 144.26950408889634;  // 100 * log2(e)
            const double nd = (double)n;
            const double mean = ts / nd;
            const double var = (tss - ts * ts / nd) / (nd - 1.0);  // ddof=1
            const double inv_std = 1.0 / sqrt(var);
            sConst[0] = (float)(0.5 * Ld * inv_std);
            sConst[1] = (float)(-0.5 * Ld * inv_std * mean);
#pragma unroll
            for (int k = 0; k < 9; ++k)
                sConst[2 + k] = (float)exp2(-0.5 * Ld * d_ZS[k]);
        }
        __syncthreads();
    }
    const float S2 = sConst[0], B2 = sConst[1];
    float sg[9];
#pragma unroll
    for (int k = 0; k < 9; ++k) sg[k] = sConst[2 + k];

    float acc[9];
#pragma unroll
    for (int k = 0; k < 9; ++k) acc[k] = 0.f;

    auto process = [&](float xv) {
        const float E = EXP2F(fmaf(xv, S2, B2));  // 2^(a/2)
#pragma unroll
        for (int k = 0; k < 9; ++k) {
            const float t = E * sg[k];  // 2^((a-C_k)/2); over/underflow exact
            acc[k] += RCPF(1.0f + t * t);
        }
    };

    const int n4 = n >> 2;
    const float4* __restrict__ x4 = (const float4*)x;

    if (n4 == NBLK * 256 * 64 && (n & 3) == 0) {
        const float4* wbase = x4 + blockIdx.x * 16384 + wid * 4096;
        float4* sbuf0 = &stage[wid][0][0];
        float4* sbuf1 = &stage[wid][1][0];
#pragma unroll
        for (int r = 0; r < 8; ++r) async_load16(wbase + r * 64 + lane, sbuf0 + r * 64);
        for (int u = 0; u < 8; ++u) {
            float4* cur = (u & 1) ? sbuf1 : sbuf0;
            float4* nxt = (u & 1) ? sbuf0 : sbuf1;
            __builtin_amdgcn_s_waitcnt(WAITCNT_VM0);
            if (u < 7) {
                const float4* gb = wbase + (u + 1) * 512;
#pragma unroll
                for (int r = 0; r < 8; ++r) async_load16(gb + r * 64 + lane, nxt + r * 64);
            }
#pragma unroll
            for (int r = 0; r < 8; ++r) {
                float4 v = cur[r * 64 + lane];
                process(v.x); process(v.y); process(v.z); process(v.w);
            }
        }
    } else {  // generic fallback (r8 path)
        const int tid = blockIdx.x * 256 + tx;
        const int nthreads = NBLK * 256;
        for (int i = tid; i < n4; i += nthreads) {
            float4 v = x4[i];
            process(v.x); process(v.y); process(v.z); process(v.w);
        }
        if (blockIdx.x == 0 && tx == 0) {
            for (int jj = n4 << 2; jj < n; ++jj) process(x[jj]);
        }
    }

    __syncthreads();  // sm reuse
#pragma unroll
    for (int k = 0; k < 9; ++k) {
        double r = wave_reduce_d((double)acc[k]);
        if (lane == 0) sm[wid][k] = r;
    }
    __syncthreads();
    if (tx < 9) {
        part2[9 * blockIdx.x + tx] = (sm[0][tx] + sm[1][tx]) + (sm[2][tx] + sm[3][tx]);
    }
}

__global__ __launch_bounds__(256) void finalize_kernel(const double* __restrict__ part2,
                                                       float* __restrict__ out, int n) {
    const int tx = threadIdx.x;
    double acc[9];
#pragma unroll
    for (int k = 0; k < 9; ++k) acc[k] = 0.0;
    for (int b = tx; b < NBLK; b += 256) {  // fixed order -> deterministic
#pragma unroll
        for (int k = 0; k < 9; ++k) acc[k] += part2[9 * b + k];
    }
    __shared__ double sm[4][9];
    const int lane = tx & 63, wid = tx >> 6;
#pragma unroll
    for (int k = 0; k < 9; ++k) {
        double r = wave_reduce_d(acc[k]);
        if (lane == 0) sm[wid][k] = r;
    }
    __syncthreads();
    if (tx == 0) {
        double cum[9];
#pragma unroll
        for (int k = 0; k < 9; ++k)
            cum[k] = (sm[0][k] + sm[1][k]) + (sm[2][k] + sm[3][k]);
        epilogue(cum, out, n);
    }
}

extern "C" void kernel_launch(void* const* d_in, const int* in_sizes, int n_in,
                              void* d_out, int out_size, void* d_ws, size_t ws_size,
                              hipStream_t stream) {
    const float* x = (const float*)d_in[0];
    const int n = in_sizes[0];
    double* part1 = (double*)d_ws;       // 2*NBLK doubles
    double* part2 = part1 + 2 * NBLK;    // 9*NBLK doubles

    pass1_stats<<<NBLK, 256, 0, stream>>>(x, part1, n);
    pass2_cum<<<NBLK, 256, 0, stream>>>(x, part1, part2, n);
    finalize_kernel<<<1, 256, 0, stream>>>(part2, (float*)d_out, n);
}